// Round 5
// baseline (970.615 us; speedup 1.0000x reference)
//
#include <hip/hip_runtime.h>

#define IC 3
#define OCH 16
#define IDD 16
#define IHH 32
#define IWW 32
#define ODD 31
#define OHH 63
#define OWW 63
#define NB 32

typedef float f2 __attribute__((ext_vector_type(2)));
typedef float f4 __attribute__((ext_vector_type(4)));

#define LOG2E 1.44269504088896340736f
#define LN2   0.69314718055994530942f

static __device__ __forceinline__ f2 fma2(f2 a, f2 b, f2 c) {
    return __builtin_elementwise_fma(a, b, c);   // -> v_pk_fma_f32
}

// Fused ConvTranspose3d(3->16,k3,s2,p1) + channel-LSE + x*sigmoid(x+3)/6 - bias, clip [-1,1].
// Parity decomposition, 2x2 patch/thread, packed-f2 oc accumulators (round-4 proven shape).
// NEW: each block handles an od-PAIR (2t: kd=1 @ plane t; 2t+1: kd=0 @ t+1, kd=2 @ t) in two
// REGISTER-DISJOINT phases separated by sched_barrier(0)  (round-2 spill lesson), with
// __launch_bounds__(256,4) capping regalloc at 128 VGPR. Halves block count (2048), amortizes
// staging, reuses plane-t x registers across phases. Weights read as ds_read_b128 (f4) and
// split into even-aligned f2 pairs (free) -> LDS inst count halved.
__global__ __launch_bounds__(256, 4) void convt_lse_kernel(
    const float* __restrict__ x, const float* __restrict__ w,
    const float* __restrict__ bias, float* __restrict__ out)
{
    __shared__ __align__(16) float wl[IC * 27 * OCH];

    const int j = threadIdx.x & 31;                       // ow pair: ow = 2j, 2j+1
    const int i = (threadIdx.x >> 5) + (blockIdx.x << 3); // oh pair: oh = 2i, 2i+1
    const int t = blockIdx.y;                             // od pair: od = 2t, 2t+1
    const int b = blockIdx.z;

    const int r0 = i * IWW;
    const int r1 = min(i + 1, IHH - 1) * IWW;  // clamp: feeds only non-stored oh=63
    const int c0 = j;
    const int c1 = min(j + 1, IWW - 1);        // clamp: feeds only non-stored ow=63

    // ---- prefetch x planes t (xa) and t+1 (xb) before staging: latency hides there.
    // xa feeds phase A (kd=1) AND phase B (kd=2); xb feeds phase B (kd=0).
    float xa[IC][4], xb[IC][4];
    const int idB = min(t + 1, IDD - 1);       // t=15: dup load, phase B skipped
    #pragma unroll
    for (int ic = 0; ic < IC; ++ic) {
        const float* __restrict__ xpA = x + (((b * IC + ic) * IDD + t) << 10);
        const float* __restrict__ xpB = x + (((b * IC + ic) * IDD + idB) << 10);
        xa[ic][0] = xpA[r0 + c0]; xa[ic][1] = xpA[r0 + c1];
        xa[ic][2] = xpA[r1 + c0]; xa[ic][3] = xpA[r1 + c1];
        xb[ic][0] = xpB[r0 + c0]; xb[ic][1] = xpB[r0 + c1];
        xb[ic][2] = xpB[r1 + c0]; xb[ic][3] = xpB[r1 + c1];
    }
    const float bv = bias[0];

    // ---- stage weights (exp2 domain): wl[(ic*27 + kd*9+kh*3+kw)*16 + oc]
    for (int idx = threadIdx.x; idx < IC * 27 * OCH; idx += 256) {
        int ic   = idx / (27 * OCH);
        int rem  = idx - ic * (27 * OCH);
        int kpos = rem >> 4;
        int oc   = rem & 15;
        wl[idx] = w[(ic * OCH + oc) * 27 + kpos] * LOG2E;
    }
    __syncthreads();

// acc[p][cp]: p 0=(even oh,even ow) 1=(eo) 2=(oe) 3=(oo); cp = oc pair
#define TAP(kd, X, first)                                                             \
    {                                                                                 \
        _Pragma("unroll")                                                             \
        for (int ic = 0; ic < IC; ++ic) {                                             \
            const f2 x00 = {X[ic][0], X[ic][0]};                                      \
            const f2 x01 = {X[ic][1], X[ic][1]};                                      \
            const f2 x10 = {X[ic][2], X[ic][2]};                                      \
            const f2 x11 = {X[ic][3], X[ic][3]};                                      \
            const f4* __restrict__ wq = (const f4*)(wl + (ic * 3 + (kd)) * 9 * OCH);  \
            _Pragma("unroll")                                                         \
            for (int q = 0; q < 4; ++q) {                                             \
                const f4 W0 = wq[0 * 4 + q], W1 = wq[1 * 4 + q], W2 = wq[2 * 4 + q],  \
                         W3 = wq[3 * 4 + q], W4 = wq[4 * 4 + q], W5 = wq[5 * 4 + q],  \
                         W6 = wq[6 * 4 + q], W7 = wq[7 * 4 + q], W8 = wq[8 * 4 + q];  \
                _Pragma("unroll")                                                     \
                for (int h = 0; h < 2; ++h) {                                         \
                    const int cp = 2 * q + h;                                         \
                    const f2 w0 = {W0[2*h], W0[2*h+1]}, w1 = {W1[2*h], W1[2*h+1]},    \
                             w2 = {W2[2*h], W2[2*h+1]}, w3 = {W3[2*h], W3[2*h+1]},    \
                             w4 = {W4[2*h], W4[2*h+1]}, w5 = {W5[2*h], W5[2*h+1]},    \
                             w6 = {W6[2*h], W6[2*h+1]}, w7 = {W7[2*h], W7[2*h+1]},    \
                             w8 = {W8[2*h], W8[2*h+1]};                               \
                    if ((first) && ic == 0) {                                         \
                        acc[3][cp] = x11 * w0;                                        \
                        acc[2][cp] = x10 * w1;                                        \
                        acc[1][cp] = x01 * w3;                                        \
                        acc[0][cp] = x00 * w4;                                        \
                    } else {                                                          \
                        acc[3][cp] = fma2(x11, w0, acc[3][cp]);                       \
                        acc[2][cp] = fma2(x10, w1, acc[2][cp]);                       \
                        acc[1][cp] = fma2(x01, w3, acc[1][cp]);                       \
                        acc[0][cp] = fma2(x00, w4, acc[0][cp]);                       \
                    }                                                                 \
                    acc[3][cp] = fma2(x10, w2, acc[3][cp]);                           \
                    acc[1][cp] = fma2(x00, w5, acc[1][cp]);                           \
                    acc[3][cp] = fma2(x01, w6, acc[3][cp]);                           \
                    acc[2][cp] = fma2(x00, w7, acc[2][cp]);                           \
                    acc[3][cp] = fma2(x00, w8, acc[3][cp]);                           \
                }                                                                     \
            }                                                                         \
        }                                                                             \
    }

    auto finish = [&](f2 (&acc)[4][8], int od) {
        const int oh0   = 2 * i;
        const int ow0   = 2 * j;
        const int obase = (b * ODD + od) * OHH;
        #pragma unroll
        for (int p = 0; p < 4; ++p) {
            const int oh = oh0 + (p >> 1);
            const int ow = ow0 + (p & 1);
            if (oh < OHH && ow < OWW) {
                // acc in log2 domain: S = sum exp2(acc); no max-sub (|conv| << 88*ln2)
                f2 sa = {0.0f, 0.0f}, sb = {0.0f, 0.0f};
                #pragma unroll
                for (int cp = 0; cp < 8; cp += 2) {
                    f2 ea, eb;
                    ea.x = __builtin_amdgcn_exp2f(acc[p][cp].x);
                    ea.y = __builtin_amdgcn_exp2f(acc[p][cp].y);
                    eb.x = __builtin_amdgcn_exp2f(acc[p][cp + 1].x);
                    eb.y = __builtin_amdgcn_exp2f(acc[p][cp + 1].y);
                    sa += ea;
                    sb += eb;
                }
                const f2 st   = sa + sb;
                const float S = st.x + st.y;
                const float v = LN2 * __builtin_amdgcn_logf(S);
                const float e = __builtin_amdgcn_exp2f(fmaf(-LOG2E, v, -3.0f * LOG2E));
                const float hs = v * __builtin_amdgcn_rcpf(fmaf(6.0f, e, 6.0f));
                const float r  = fminf(1.0f, fmaxf(-1.0f, hs - bv));
                out[(obase + oh) * OWW + ow] = r;
            }
        }
    };

    {   // ---- phase A: od = 2t (even), kd=1 @ plane t
        f2 acc[4][8];
        TAP(1, xa, true)
        finish(acc, 2 * t);
    }
    __builtin_amdgcn_sched_barrier(0);   // hard fence: no cross-phase live-range merge
    if (t < 15) {   // ---- phase B: od = 2t+1 (odd), kd=0 @ t+1, kd=2 @ t
        f2 acc[4][8];
        TAP(0, xb, true)
        TAP(2, xa, false)
        finish(acc, 2 * t + 1);
    }
}

extern "C" void kernel_launch(void* const* d_in, const int* in_sizes, int n_in,
                              void* d_out, int out_size, void* d_ws, size_t ws_size,
                              hipStream_t stream) {
    const float* x    = (const float*)d_in[0];
    const float* w    = (const float*)d_in[1];
    const float* bias = (const float*)d_in[2];
    float* out        = (float*)d_out;

    dim3 grid(4, 16, NB);   // 4 i-chunks x od-pairs x batch = 2048 blocks
    dim3 block(256);
    convt_lse_kernel<<<grid, block, 0, stream>>>(x, w, bias, out);
}

// Round 6
// 97.844 us; speedup vs baseline: 9.9200x; 9.9200x over previous
//
#include <hip/hip_runtime.h>

#define IC 3
#define OCH 16
#define IDD 16
#define IHH 32
#define IWW 32
#define ODD 31
#define OHH 63
#define OWW 63
#define NB 32

typedef float f2 __attribute__((ext_vector_type(2)));

#define LOG2E 1.44269504088896340736f
#define LN2   0.69314718055994530942f

static __device__ __forceinline__ f2 fma2(f2 a, f2 b, f2 c) {
    return __builtin_elementwise_fma(a, b, c);   // -> v_pk_fma_f32
}

// Fused ConvTranspose3d(3->16,k3,s2,p1) + channel-LSE + x*sigmoid(x+3)/6 - bias, clip [-1,1].
// Per-thread code is EXACTLY round-4's proven shape (2x2 patch, one od, packed-f2 acc at
// function scope, macro-only access -- no lambda/array-ref: round-5's scratch lesson).
// NEW: 512-thread blocks; threads 0-255 do od=2t, threads 256-511 do od=2t+1 (wave-uniform).
// Halves workgroup count (2048), amortizes weight staging over 2 od-planes, shares plane-t
// x-reads via L1 between halves, and attacks the launch/drain churn behind 31% occupancy.
__global__ __launch_bounds__(512) void convt_lse_kernel(
    const float* __restrict__ x, const float* __restrict__ w,
    const float* __restrict__ bias, float* __restrict__ out)
{
    __shared__ __align__(16) float wl[IC * 27 * OCH];

    const int tid  = threadIdx.x & 255;
    const int half = threadIdx.x >> 8;                   // 0: even od, 1: odd od
    const int j  = tid & 31;                             // ow pair: ow = 2j, 2j+1
    const int i  = (tid >> 5) + (blockIdx.x << 3);       // oh pair: oh = 2i, 2i+1
    const int od = (blockIdx.y << 1) + half;             // 0..31; od=31 guarded below
    const int b  = blockIdx.z;

    const int ih0 = i;
    const int ih1 = min(i + 1, IHH - 1);   // clamp: feeds only non-stored oh=63
    const int iw0 = j;
    const int iw1 = min(j + 1, IWW - 1);   // clamp: feeds only non-stored ow=63

    const bool odd  = half != 0;
    const bool live = od < ODD;                          // od=31 half: compute junk, never store
    const int id0 = min(odd ? ((od + 1) >> 1) : (od >> 1), IDD - 1);
    const int id1 = (od - 1) >> 1;         // used only when odd; od>=1 there

    // ---- x prefetch: issue global loads before staging so latency hides under it
    float xr[2][IC][4];    // [tap][ic][{00,01,10,11}] - all indices compile-time below
    #pragma unroll
    for (int ic = 0; ic < IC; ++ic) {
        const float* __restrict__ xp = x + (((b * IC + ic) * IDD + id0) << 10);
        xr[0][ic][0] = xp[ih0 * IWW + iw0];
        xr[0][ic][1] = xp[ih0 * IWW + iw1];
        xr[0][ic][2] = xp[ih1 * IWW + iw0];
        xr[0][ic][3] = xp[ih1 * IWW + iw1];
    }
    if (odd) {
        #pragma unroll
        for (int ic = 0; ic < IC; ++ic) {
            const float* __restrict__ xp = x + (((b * IC + ic) * IDD + id1) << 10);
            xr[1][ic][0] = xp[ih0 * IWW + iw0];
            xr[1][ic][1] = xp[ih0 * IWW + iw1];
            xr[1][ic][2] = xp[ih1 * IWW + iw0];
            xr[1][ic][3] = xp[ih1 * IWW + iw1];
        }
    }
    const float bv = bias[0];

    // ---- stage weights (scaled to exp2 domain): [ic][kd][kh*3+kw][oc]
    for (int idx = threadIdx.x; idx < IC * 27 * OCH; idx += 512) {
        int ic   = idx / (27 * OCH);
        int rem  = idx - ic * (27 * OCH);
        int kpos = rem >> 4;   // kd*9 + kh*3 + kw
        int oc   = rem & 15;
        wl[idx] = w[(ic * OCH + oc) * 27 + kpos] * LOG2E;
    }
    __syncthreads();

    // acc[p][cp]: p 0=(ee) 1=(eo) 2=(oe) 3=(oo); cp = oc pair (2 channels)
    f2 acc[4][8];

#define EMIT(first, x00, x01, x10, x11, wp2)                                          \
    {                                                                                 \
        _Pragma("unroll")                                                             \
        for (int cp = 0; cp < 8; ++cp) {                                              \
            const f2 w0 = wp2[0 * 8 + cp], w1 = wp2[1 * 8 + cp], w2 = wp2[2 * 8 + cp],\
                     w3 = wp2[3 * 8 + cp], w4 = wp2[4 * 8 + cp], w5 = wp2[5 * 8 + cp],\
                     w6 = wp2[6 * 8 + cp], w7 = wp2[7 * 8 + cp], w8 = wp2[8 * 8 + cp];\
            if (first) {                                                              \
                acc[3][cp] = x11 * w0;                                                \
                acc[2][cp] = x10 * w1;                                                \
                acc[1][cp] = x01 * w3;                                                \
                acc[0][cp] = x00 * w4;                                                \
            } else {                                                                  \
                acc[3][cp] = fma2(x11, w0, acc[3][cp]);                               \
                acc[2][cp] = fma2(x10, w1, acc[2][cp]);                               \
                acc[1][cp] = fma2(x01, w3, acc[1][cp]);                               \
                acc[0][cp] = fma2(x00, w4, acc[0][cp]);                               \
            }                                                                         \
            acc[3][cp] = fma2(x10, w2, acc[3][cp]);                                   \
            acc[1][cp] = fma2(x00, w5, acc[1][cp]);                                   \
            acc[3][cp] = fma2(x01, w6, acc[3][cp]);                                   \
            acc[2][cp] = fma2(x00, w7, acc[2][cp]);                                   \
            acc[3][cp] = fma2(x00, w8, acc[3][cp]);                                   \
        }                                                                             \
    }

#define DO_TAP(kd, tpi, first)                                                        \
    {                                                                                 \
        _Pragma("unroll")                                                             \
        for (int ic = 0; ic < IC; ++ic) {                                             \
            const f2 x00 = {xr[tpi][ic][0], xr[tpi][ic][0]};                          \
            const f2 x01 = {xr[tpi][ic][1], xr[tpi][ic][1]};                          \
            const f2 x10 = {xr[tpi][ic][2], xr[tpi][ic][2]};                          \
            const f2 x11 = {xr[tpi][ic][3], xr[tpi][ic][3]};                          \
            const f2* __restrict__ wp2 = (const f2*)(wl + (ic * 3 + (kd)) * 9 * OCH); \
            EMIT((first) && ic == 0, x00, x01, x10, x11, wp2)                         \
        }                                                                             \
    }

    if (odd) {          // odd od: kd=0 @ id0=(od+1)/2, kd=2 @ id1=(od-1)/2
        DO_TAP(0, 0, true)
        DO_TAP(2, 1, false)
    } else {            // even od: kd=1 @ id0=od/2
        DO_TAP(1, 0, true)
    }

    const int oh0   = 2 * i;
    const int ow0   = 2 * j;
    const int obase = (b * ODD + od) * OHH;

    if (live) {
        #pragma unroll
        for (int p = 0; p < 4; ++p) {
            const int oh = oh0 + (p >> 1);
            const int ow = ow0 + (p & 1);
            if (oh < OHH && ow < OWW) {
                // acc is log2-domain: sum of exp2, two packed partial sums
                f2 sa = {0.0f, 0.0f}, sb = {0.0f, 0.0f};
                #pragma unroll
                for (int cp = 0; cp < 8; cp += 2) {
                    f2 ea, eb;
                    ea.x = __builtin_amdgcn_exp2f(acc[p][cp].x);
                    ea.y = __builtin_amdgcn_exp2f(acc[p][cp].y);
                    eb.x = __builtin_amdgcn_exp2f(acc[p][cp + 1].x);
                    eb.y = __builtin_amdgcn_exp2f(acc[p][cp + 1].y);
                    sa += ea;                       // v_pk_add_f32
                    sb += eb;
                }
                const f2 st   = sa + sb;
                const float S = st.x + st.y;
                const float v = LN2 * __builtin_amdgcn_logf(S);          // ln(S)
                // hardswish-ish: v / (6*(1+exp(-(v+3)))); exp via exp2(fma)
                const float t   = __builtin_amdgcn_exp2f(fmaf(-LOG2E, v, -3.0f * LOG2E));
                const float den = fmaf(6.0f, t, 6.0f);
                const float hs  = v * __builtin_amdgcn_rcpf(den);
                const float r   = fminf(1.0f, fmaxf(-1.0f, hs - bv));
                out[(obase + oh) * OWW + ow] = r;
            }
        }
    }
}

extern "C" void kernel_launch(void* const* d_in, const int* in_sizes, int n_in,
                              void* d_out, int out_size, void* d_ws, size_t ws_size,
                              hipStream_t stream) {
    const float* x    = (const float*)d_in[0];
    const float* w    = (const float*)d_in[1];
    const float* bias = (const float*)d_in[2];
    float* out        = (float*)d_out;

    dim3 grid(4, 16, NB);   // 4 i-chunks x od-pairs x batch = 2048 blocks of 512
    dim3 block(512);
    convt_lse_kernel<<<grid, block, 0, stream>>>(x, w, bias, out);
}